// Round 5
// baseline (541.907 us; speedup 1.0000x reference)
//
#include <hip/hip_runtime.h>
#include <cstdint>
#include <cstddef>

typedef unsigned short u16;
typedef __bf16 bf16x8 __attribute__((ext_vector_type(8)));
typedef float f32x4 __attribute__((ext_vector_type(4)));
typedef short short8 __attribute__((ext_vector_type(8)));

#define DEVI static __device__ __forceinline__

DEVI u16 f2bf(float f) {
    unsigned u = __builtin_bit_cast(unsigned, f);
    u += 0x7fffu + ((u >> 16) & 1u);
    return (u16)(u >> 16);
}
DEVI float bf2f(u16 h) {
    unsigned u = ((unsigned)h) << 16;
    return __builtin_bit_cast(float, u);
}

namespace cfg {
constexpr int B = 2, T = 2048, BT = 4096, D = 2048, QL = 1536, KVL = 512, H = 16;
constexpr int DQK = 192, DROPE = 64, DV = 128, HD = H * DQK, KVD = H * 256;
constexpr int NCAT = 2176;  // QL + KVL + DROPE (2112) padded to 17*128
}

// ---------------- f32 -> bf16 flat convert ----------------
__global__ void cvt_bf16_k(const float* __restrict__ in, u16* __restrict__ out, int n4) {
    for (int i = blockIdx.x * blockDim.x + threadIdx.x; i < n4; i += gridDim.x * blockDim.x) {
        float4 v = reinterpret_cast<const float4*>(in)[i];
        ushort4 o;
        o.x = f2bf(v.x); o.y = f2bf(v.y); o.z = f2bf(v.z); o.w = f2bf(v.w);
        reinterpret_cast<ushort4*>(out)[i] = o;
    }
}

// ---------- transpose+convert: in[R][C] f32 -> out[C][R] bf16 ----------
__global__ void transpose_cvt_k(const float* __restrict__ in, u16* __restrict__ out, int R, int C) {
    __shared__ float tile[32][33];
    int tx = threadIdx.x & 31, ty = threadIdx.x >> 5;  // 256 threads
    int c0 = blockIdx.x * 32, r0 = blockIdx.y * 32;
#pragma unroll
    for (int j = 0; j < 4; ++j)
        tile[ty + j * 8][tx] = in[(size_t)(r0 + ty + j * 8) * C + c0 + tx];
    __syncthreads();
#pragma unroll
    for (int j = 0; j < 4; ++j)
        out[(size_t)(c0 + ty + j * 8) * R + r0 + tx] = f2bf(tile[tx][ty + j * 8]);
}

// ---------------- RMSNorm (bf16 in, f32 w, bf16 out), strided input ----------------
__global__ void rmsnorm_k(const u16* __restrict__ x, const float* __restrict__ w,
                          u16* __restrict__ y, int C, int xs) {
    int row = blockIdx.x, tid = threadIdx.x;
    const u16* xr = x + (size_t)row * xs;
    u16* yr = y + (size_t)row * C;
    float ss = 0.f;
    for (int i = tid; i < C; i += 256) { float v = bf2f(xr[i]); ss += v * v; }
#pragma unroll
    for (int m = 32; m >= 1; m >>= 1) ss += __shfl_xor(ss, m);
    __shared__ float red[4];
    if ((tid & 63) == 0) red[tid >> 6] = ss;
    __syncthreads();
    float tot = red[0] + red[1] + red[2] + red[3];
    float rs = rsqrtf(tot / C + 1e-6f);
    for (int i = tid; i < C; i += 256) yr[i] = f2bf(bf2f(xr[i]) * rs * w[i]);
}

// ---------------- RoPE tables ----------------
__global__ void rope_tab_k(float* __restrict__ ct, float* __restrict__ st) {
    int idx = blockIdx.x * 256 + threadIdx.x;  // T*32 total
    int t = idx >> 5, i = idx & 31;
    float inv = powf(10000.f, -(float)i / 32.f);
    float f = (float)t * inv;
    ct[idx] = cosf(f);
    st[idx] = sinf(f);
}

// ---------------- RoPE apply (in-place on bf16 rows) ----------------
__global__ void rope_apply_k(u16* __restrict__ x, const float* __restrict__ ct,
                             const float* __restrict__ st, int nrows, int rstride,
                             int roff, int rows_per_t) {
    int idx = blockIdx.x * 256 + threadIdx.x;
    if (idx >= nrows * 32) return;
    int row = idx >> 5, i = idx & 31;
    int t = (row / rows_per_t) % cfg::T;
    u16* p = x + (size_t)row * rstride + roff;
    float x1 = bf2f(p[i]), x2 = bf2f(p[32 + i]);
    float c = ct[t * 32 + i], s = st[t * 32 + i];
    p[i] = f2bf(x1 * c - x2 * s);
    p[32 + i] = f2bf(x2 * c + x1 * s);
}

// -------- V transpose: kv[b,t,h,128+d] -> vt[(b*H+h)*128+d][t] (bf16) --------
__global__ __launch_bounds__(256) void vtrans_k(const u16* __restrict__ kv,
                                                u16* __restrict__ vt) {
    using namespace cfg;
    __shared__ u16 tl[64][136];
    const int bh = blockIdx.x, t0 = blockIdx.y * 64;
    const int b = bh >> 4, h = bh & 15;
    const int tid = threadIdx.x;
#pragma unroll
    for (int it = 0; it < 4; ++it) {
        int id = tid + it * 256, r = id >> 4, c8 = id & 15;
        short8 v = *reinterpret_cast<const short8*>(
            kv + ((size_t)(b * T + t0 + r) * H + h) * 256 + 128 + c8 * 8);
        *reinterpret_cast<short8*>(&tl[r][c8 * 8]) = v;
    }
    __syncthreads();
#pragma unroll
    for (int it = 0; it < 4; ++it) {
        int id = tid + it * 256, d = id >> 3, tc = id & 7;
        short8 v;
#pragma unroll
        for (int j = 0; j < 8; ++j) v[j] = (short)tl[tc * 8 + j][d];
        *reinterpret_cast<short8*>(vt + ((size_t)bh * 128 + d) * T + t0 + tc * 8) = v;
    }
}

// ---------------- GEMM: C[M,N] = A[M,K] * Bt[N,K]^T (bf16 in, f32 acc) ----------------
// cscale multiplies the accumulator in the epilogue (used to fold the attention
// score scale * log2(e) into Q).
template <int BM, int BN, int BK, int WM, int WN, bool OUTF32>
__global__ __launch_bounds__((BM / WM) * (BN / WN) * 64) void gemm_bt_k(
    const u16* __restrict__ A, const u16* __restrict__ Bt, void* __restrict__ Cv,
    int M, int N, int K, float cscale) {
    constexpr int NW = (BM / WM) * (BN / WN);
    constexpr int MFR = WM / 16, NFR = WN / 16;
    constexpr int NWN = BN / WN;
    __shared__ u16 As[BM * BK];
    __shared__ u16 Bs[BN * BK];
    const int tid = threadIdx.x, lane = tid & 63, wid = tid >> 6;
    const int wr = wid / NWN, wc = wid % NWN;
    const int tM = blockIdx.x * BM, tN = blockIdx.y * BN;
    const int lr = lane & 15, hi = lane >> 4;
    f32x4 acc[MFR][NFR] = {};
    for (int k0 = 0; k0 < K; k0 += BK) {
        constexpr int ACH = BM * BK * 2 / NW;  // bytes per wave
#pragma unroll
        for (int c = 0; c < ACH / 1024; ++c) {
            int loff = wid * ACH + c * 1024;
            int eidx = (loff >> 1) + lane * 8;
            const u16* src = A + (size_t)(tM + eidx / BK) * K + k0 + (eidx % BK);
            __builtin_amdgcn_global_load_lds(
                (const __attribute__((address_space(1))) void*)src,
                (__attribute__((address_space(3))) void*)((char*)As + loff), 16, 0, 0);
        }
        constexpr int BCH = BN * BK * 2 / NW;
#pragma unroll
        for (int c = 0; c < BCH / 1024; ++c) {
            int loff = wid * BCH + c * 1024;
            int eidx = (loff >> 1) + lane * 8;
            const u16* src = Bt + (size_t)(tN + eidx / BK) * K + k0 + (eidx % BK);
            __builtin_amdgcn_global_load_lds(
                (const __attribute__((address_space(1))) void*)src,
                (__attribute__((address_space(3))) void*)((char*)Bs + loff), 16, 0, 0);
        }
        __syncthreads();
#pragma unroll
        for (int kk = 0; kk < BK / 32; ++kk) {
            bf16x8 af[MFR], bfv[NFR];
#pragma unroll
            for (int mi = 0; mi < MFR; ++mi)
                af[mi] = *reinterpret_cast<const bf16x8*>(&As[(wr * WM + mi * 16 + lr) * BK + kk * 32 + hi * 8]);
#pragma unroll
            for (int ni = 0; ni < NFR; ++ni)
                bfv[ni] = *reinterpret_cast<const bf16x8*>(&Bs[(wc * WN + ni * 16 + lr) * BK + kk * 32 + hi * 8]);
#pragma unroll
            for (int mi = 0; mi < MFR; ++mi)
#pragma unroll
                for (int ni = 0; ni < NFR; ++ni)
                    acc[mi][ni] = __builtin_amdgcn_mfma_f32_16x16x32_bf16(af[mi], bfv[ni], acc[mi][ni], 0, 0, 0);
        }
        __syncthreads();
    }
#pragma unroll
    for (int mi = 0; mi < MFR; ++mi)
#pragma unroll
        for (int ni = 0; ni < NFR; ++ni)
#pragma unroll
            for (int r = 0; r < 4; ++r) {
                int row = tM + wr * WM + mi * 16 + hi * 4 + r;
                int col = tN + wc * WN + ni * 16 + lr;
                float v = acc[mi][ni][r] * cscale;
                if (OUTF32)
                    ((float*)Cv)[(size_t)row * N + col] = v;
                else
                    ((u16*)Cv)[(size_t)row * N + col] = f2bf(v);
            }
}

// ---------------- Flash attention (causal, bf16, MFMA) ----------------
// QB=64, KB=64, 4 waves (16 q-rows each). One q-tile per block, launched
// largest-first (bid>>5 -> qt descending). Q is pre-scaled by
// (1/sqrt(192))*log2(e) in the q_b GEMM epilogue, so P = exp2(S) directly.
// FIXED-max softmax: no online max tracking / rescale (scores bounded ~|100|
// raw -> P <= ~2^11, sums <= ~2^26: f32-safe; softmax is scale-invariant).
namespace acfg {
constexpr int QB = 64, KB = 64, KS = 200, VTS = 72, PS = 72;
constexpr int NQT = cfg::T / QB;  // 32
}
__global__ __launch_bounds__(256) void mla_attn_k(const u16* __restrict__ q,
                                                  const u16* __restrict__ kv,
                                                  const u16* __restrict__ kr, int krs,
                                                  const u16* __restrict__ vtg,
                                                  u16* __restrict__ o) {
    using namespace cfg;
    using namespace acfg;
    __shared__ u16 Ks[KB * KS];       // 64 x 192 (stride 200)
    __shared__ u16 Vt[DV * VTS];      // 128 x 64 (stride 72), pre-transposed
    __shared__ u16 Pl[4 * 16 * PS];   // per-wave 16 x 64 (stride 72)
    const int bid = blockIdx.x;
    const int bh = bid & 31;
    const int qt = NQT - 1 - (bid >> 5);  // biggest blocks first
    const int b = bh >> 4, h = bh & 15;
    const int q0 = qt * QB;
    const int tid = threadIdx.x, lane = tid & 63, w = tid >> 6;
    const int lr = lane & 15, hi = lane >> 4;

    bf16x8 qf[6];
    {
        int row = q0 + w * 16 + lr;
        const u16* qp = q + ((size_t)(b * T + row) * H + h) * DQK;
#pragma unroll
        for (int ks = 0; ks < 6; ++ks)
            qf[ks] = *reinterpret_cast<const bf16x8*>(qp + ks * 32 + hi * 8);
    }
    f32x4 oacc[8] = {};
    float lsum[4] = {0.f, 0.f, 0.f, 0.f};

    const int nkb = qt + 1;
#pragma unroll 1
    for (int kb = 0; kb < nkb; ++kb) {
        const int kt0 = kb * KB;
        // stage K nope part (64 rows x 128)
#pragma unroll
        for (int it = 0; it < 4; ++it) {
            int id = tid + it * 256, r = id >> 4, c8 = id & 15;
            short8 v = *reinterpret_cast<const short8*>(
                kv + ((size_t)(b * T + kt0 + r) * H + h) * 256 + c8 * 8);
            *reinterpret_cast<short8*>(&Ks[r * KS + c8 * 8]) = v;
        }
        // stage K rope part (64 rows x 64)
#pragma unroll
        for (int it = 0; it < 2; ++it) {
            int id = tid + it * 256, r = id >> 3, c8 = id & 7;
            short8 v = *reinterpret_cast<const short8*>(
                kr + (size_t)(b * T + kt0 + r) * krs + c8 * 8);
            *reinterpret_cast<short8*>(&Ks[r * KS + 128 + c8 * 8]) = v;
        }
        // stage V (pre-transposed in global): rows d, cols t
#pragma unroll
        for (int it = 0; it < 4; ++it) {
            int id = tid + it * 256, d = id >> 3, c8 = id & 7;
            short8 v = *reinterpret_cast<const short8*>(
                vtg + ((size_t)(b * H + h) * 128 + d) * T + kt0 + c8 * 8);
            *reinterpret_cast<short8*>(&Vt[d * VTS + c8 * 8]) = v;
        }
        __syncthreads();

        // S = Q K^T  (per wave: 16 q-rows x 64 k-cols), already in log2 units
        f32x4 s[4] = {};
#pragma unroll
        for (int ks = 0; ks < 6; ++ks) {
            bf16x8 kf[4];
#pragma unroll
            for (int ni = 0; ni < 4; ++ni)
                kf[ni] = *reinterpret_cast<const bf16x8*>(&Ks[(ni * 16 + lr) * KS + ks * 32 + hi * 8]);
#pragma unroll
            for (int ni = 0; ni < 4; ++ni)
                s[ni] = __builtin_amdgcn_mfma_f32_16x16x32_bf16(qf[ks], kf[ni], s[ni], 0, 0, 0);
        }
        const bool diag = (kb == nkb - 1);
        if (diag) {
#pragma unroll
            for (int r = 0; r < 4; ++r) {
                int qr = q0 + w * 16 + hi * 4 + r;
#pragma unroll
                for (int ni = 0; ni < 4; ++ni) {
                    int kc = kt0 + ni * 16 + lr;
                    if (kc > qr) s[ni][r] = -INFINITY;
                }
            }
        }
        // fixed-max softmax: P = exp2(S); accumulate per-lane partial row sums
        u16* pw = &Pl[w * 16 * PS];
#pragma unroll
        for (int r = 0; r < 4; ++r) {
            float p0 = exp2f(s[0][r]);
            float p1 = exp2f(s[1][r]);
            float p2 = exp2f(s[2][r]);
            float p3 = exp2f(s[3][r]);
            lsum[r] += (p0 + p1) + (p2 + p3);
            pw[(hi * 4 + r) * PS + 0 * 16 + lr] = __builtin_bit_cast(u16, (__bf16)p0);
            pw[(hi * 4 + r) * PS + 1 * 16 + lr] = __builtin_bit_cast(u16, (__bf16)p1);
            pw[(hi * 4 + r) * PS + 2 * 16 + lr] = __builtin_bit_cast(u16, (__bf16)p2);
            pw[(hi * 4 + r) * PS + 3 * 16 + lr] = __builtin_bit_cast(u16, (__bf16)p3);
        }
        // PV
#pragma unroll
        for (int kk = 0; kk < 2; ++kk) {
            bf16x8 pf = *reinterpret_cast<const bf16x8*>(&pw[lr * PS + kk * 32 + hi * 8]);
#pragma unroll
            for (int ni = 0; ni < 8; ++ni) {
                bf16x8 vf = *reinterpret_cast<const bf16x8*>(&Vt[(ni * 16 + lr) * VTS + kk * 32 + hi * 8]);
                oacc[ni] = __builtin_amdgcn_mfma_f32_16x16x32_bf16(pf, vf, oacc[ni], 0, 0, 0);
            }
        }
        __syncthreads();
    }
    // final row-sum reduce across the 16-lane group, then normalize + store
    float ltot[4];
#pragma unroll
    for (int r = 0; r < 4; ++r) {
        float sumv = lsum[r];
        sumv += __shfl_xor(sumv, 1);
        sumv += __shfl_xor(sumv, 2);
        sumv += __shfl_xor(sumv, 4);
        sumv += __shfl_xor(sumv, 8);
        ltot[r] = 1.f / sumv;
    }
#pragma unroll
    for (int ni = 0; ni < 8; ++ni)
#pragma unroll
        for (int r = 0; r < 4; ++r) {
            int row = q0 + w * 16 + hi * 4 + r;
            int col = ni * 16 + lr;
            float v = oacc[ni][r] * ltot[r];
            o[((size_t)(b * T + row) * H + h) * DV + col] = f2bf(v);
        }
}

// ---------------- workspace layout ----------------
namespace wso {
using namespace cfg;
constexpr size_t O_HSVT = 0;  // hs_b (stage-1 input), later aliased by vt
constexpr size_t O_WCAT = O_HSVT + (size_t)BT * D * 2;
constexpr size_t O_WQB  = O_WCAT + (size_t)NCAT * D * 2;
constexpr size_t O_WKVB = O_WQB  + (size_t)HD * QL * 2;
constexpr size_t O_WO   = O_WKVB + (size_t)KVD * KVL * 2;
constexpr size_t O_QAKR = O_WO   + (size_t)D * D * 2;
constexpr size_t O_QAN  = O_QAKR + (size_t)BT * NCAT * 2;
constexpr size_t O_KVAN = O_QAN;  // alias: qan dead before kvan is written
constexpr size_t O_QB   = O_QAN  + (size_t)BT * QL * 2;
constexpr size_t O_KV   = O_QB   + (size_t)BT * HD * 2;
constexpr size_t O_COS  = O_KV   + (size_t)BT * KVD * 2;
constexpr size_t O_SIN  = O_COS  + (size_t)T * 32 * 4;
constexpr size_t O_OB   = O_SIN  + (size_t)T * 32 * 4;
}

extern "C" void kernel_launch(void* const* d_in, const int* in_sizes, int n_in,
                              void* d_out, int out_size, void* d_ws, size_t ws_size,
                              hipStream_t stream) {
    using namespace cfg;
    using namespace wso;
    (void)in_sizes; (void)n_in; (void)out_size; (void)ws_size;

    const float* hs   = (const float*)d_in[0];
    const float* Wqa  = (const float*)d_in[1];
    const float* qnw  = (const float*)d_in[2];
    const float* Wqb  = (const float*)d_in[3];
    const float* Wkr  = (const float*)d_in[4];
    const float* Wkva = (const float*)d_in[5];
    const float* kvnw = (const float*)d_in[6];
    const float* Wkvb = (const float*)d_in[7];
    const float* Wo   = (const float*)d_in[8];

    char* ws = (char*)d_ws;
    u16* hs_b   = (u16*)(ws + O_HSVT);
    u16* vtg    = (u16*)(ws + O_HSVT);  // alias: hs_b dead after stage-1 GEMM
    u16* wcat   = (u16*)(ws + O_WCAT);
    u16* wqb_t  = (u16*)(ws + O_WQB);
    u16* wkvb_t = (u16*)(ws + O_WKVB);
    u16* wo_t   = (u16*)(ws + O_WO);
    u16* qakr   = (u16*)(ws + O_QAKR);
    u16* qan    = (u16*)(ws + O_QAN);
    u16* kvan   = (u16*)(ws + O_KVAN);
    u16* qb     = (u16*)(ws + O_QB);
    u16* kvb    = (u16*)(ws + O_KV);
    float* cost = (float*)(ws + O_COS);
    float* sint = (float*)(ws + O_SIN);
    u16* ob     = (u16*)(ws + O_OB);

    // attention score scale * log2(e), folded into Q via the q_b GEMM epilogue
    const float qesc = 0.07216878364870323f * 1.4426950408889634f;

    // 1. convert hidden to bf16
    cvt_bf16_k<<<2048, 256, 0, stream>>>(hs, hs_b, BT * D / 4);
    // 2. transpose-convert weights; wcat = [Wq_a | Wkv_a | Wk_rope]^T rows
    transpose_cvt_k<<<dim3(QL / 32, D / 32), 256, 0, stream>>>(Wqa, wcat, D, QL);
    transpose_cvt_k<<<dim3(KVL / 32, D / 32), 256, 0, stream>>>(Wkva, wcat + (size_t)QL * D, D, KVL);
    transpose_cvt_k<<<dim3(DROPE / 32, D / 32), 256, 0, stream>>>(Wkr, wcat + (size_t)(QL + KVL) * D, D, DROPE);
    transpose_cvt_k<<<dim3(HD / 32, QL / 32), 256, 0, stream>>>(Wqb, wqb_t, QL, HD);
    transpose_cvt_k<<<dim3(KVD / 32, KVL / 32), 256, 0, stream>>>(Wkvb, wkvb_t, KVL, KVD);
    transpose_cvt_k<<<dim3(D / 32, D / 32), 256, 0, stream>>>(Wo, wo_t, D, D);
    // 3. rope tables
    rope_tab_k<<<T * 32 / 256, 256, 0, stream>>>(cost, sint);
    // 4. fused stage-1: qakr = hidden @ [Wq_a|Wkv_a|Wk_rope]
    gemm_bt_k<128, 128, 32, 64, 64, false><<<dim3(BT / 128, NCAT / 128), 256, 0, stream>>>(
        hs_b, wcat, qakr, BT, NCAT, D, 1.f);
    // 5. q branch: rmsnorm -> q_b (epilogue-scaled by qesc) -> rope
    rmsnorm_k<<<BT, 256, 0, stream>>>(qakr, qnw, qan, QL, NCAT);
    gemm_bt_k<128, 128, 32, 64, 64, false><<<dim3(BT / 128, HD / 128), 256, 0, stream>>>(
        qan, wqb_t, qb, BT, HD, QL, qesc);
    rope_apply_k<<<BT * H * 32 / 256, 256, 0, stream>>>(qb, cost, sint, BT * H, DQK, 128, H);
    // 6. kv branch: rmsnorm -> kv_b
    rmsnorm_k<<<BT, 256, 0, stream>>>(qakr + QL, kvnw, kvan, KVL, NCAT);
    gemm_bt_k<128, 128, 32, 64, 64, false><<<dim3(BT / 128, KVD / 128), 256, 0, stream>>>(
        kvan, wkvb_t, kvb, BT, KVD, KVL, 1.f);
    // 7. rope on k_rope slice (in place in qakr)
    rope_apply_k<<<BT * 32 / 256, 256, 0, stream>>>(qakr + QL + KVL, cost, sint, BT, NCAT, 0, 1);
    // 8. global V transpose, then attention (1 q-tile/block, biggest first)
    vtrans_k<<<dim3(B * H, T / 64), 256, 0, stream>>>(kvb, vtg);
    mla_attn_k<<<32 * acfg::NQT, 256, 0, stream>>>(qb, kvb, qakr + QL + KVL, NCAT, vtg, ob);
    // 9. out = o @ Wo  (f32 out)
    gemm_bt_k<128, 128, 32, 64, 64, true><<<dim3(BT / 128, D / 128), 256, 0, stream>>>(
        ob, wo_t, d_out, BT, D, H * DV, 1.f);
}

// Round 6
// 448.731 us; speedup vs baseline: 1.2076x; 1.2076x over previous
//
#include <hip/hip_runtime.h>
#include <cstdint>
#include <cstddef>

typedef unsigned short u16;
typedef __bf16 bf16x8 __attribute__((ext_vector_type(8)));
typedef float f32x4 __attribute__((ext_vector_type(4)));
typedef short short8 __attribute__((ext_vector_type(8)));

#define DEVI static __device__ __forceinline__

DEVI u16 f2bf(float f) {
    unsigned u = __builtin_bit_cast(unsigned, f);
    u += 0x7fffu + ((u >> 16) & 1u);
    return (u16)(u >> 16);
}
DEVI float bf2f(u16 h) {
    unsigned u = ((unsigned)h) << 16;
    return __builtin_bit_cast(float, u);
}

namespace cfg {
constexpr int B = 2, T = 2048, BT = 4096, D = 2048, QL = 1536, KVL = 512, H = 16;
constexpr int DQK = 192, DROPE = 64, DV = 128, HD = H * DQK, KVD = H * 256;
constexpr int NCAT = 2176;  // QL + KVL + DROPE (2112) padded to 17*128
}

// ---------------- f32 -> bf16 flat convert ----------------
__global__ void cvt_bf16_k(const float* __restrict__ in, u16* __restrict__ out, int n4) {
    for (int i = blockIdx.x * blockDim.x + threadIdx.x; i < n4; i += gridDim.x * blockDim.x) {
        float4 v = reinterpret_cast<const float4*>(in)[i];
        ushort4 o;
        o.x = f2bf(v.x); o.y = f2bf(v.y); o.z = f2bf(v.z); o.w = f2bf(v.w);
        reinterpret_cast<ushort4*>(out)[i] = o;
    }
}

// ---------- transpose+convert: in[R][C] f32 -> out[C][R] bf16 ----------
__global__ void transpose_cvt_k(const float* __restrict__ in, u16* __restrict__ out, int R, int C) {
    __shared__ float tile[32][33];
    int tx = threadIdx.x & 31, ty = threadIdx.x >> 5;  // 256 threads
    int c0 = blockIdx.x * 32, r0 = blockIdx.y * 32;
#pragma unroll
    for (int j = 0; j < 4; ++j)
        tile[ty + j * 8][tx] = in[(size_t)(r0 + ty + j * 8) * C + c0 + tx];
    __syncthreads();
#pragma unroll
    for (int j = 0; j < 4; ++j)
        out[(size_t)(c0 + ty + j * 8) * R + r0 + tx] = f2bf(tile[tx][ty + j * 8]);
}

// ---------------- RMSNorm (bf16 in, f32 w, bf16 out), strided input ----------------
__global__ void rmsnorm_k(const u16* __restrict__ x, const float* __restrict__ w,
                          u16* __restrict__ y, int C, int xs) {
    int row = blockIdx.x, tid = threadIdx.x;
    const u16* xr = x + (size_t)row * xs;
    u16* yr = y + (size_t)row * C;
    float ss = 0.f;
    for (int i = tid; i < C; i += 256) { float v = bf2f(xr[i]); ss += v * v; }
#pragma unroll
    for (int m = 32; m >= 1; m >>= 1) ss += __shfl_xor(ss, m);
    __shared__ float red[4];
    if ((tid & 63) == 0) red[tid >> 6] = ss;
    __syncthreads();
    float tot = red[0] + red[1] + red[2] + red[3];
    float rs = rsqrtf(tot / C + 1e-6f);
    for (int i = tid; i < C; i += 256) yr[i] = f2bf(bf2f(xr[i]) * rs * w[i]);
}

// ---------------- RoPE tables ----------------
__global__ void rope_tab_k(float* __restrict__ ct, float* __restrict__ st) {
    int idx = blockIdx.x * 256 + threadIdx.x;  // T*32 total
    int t = idx >> 5, i = idx & 31;
    float inv = powf(10000.f, -(float)i / 32.f);
    float f = (float)t * inv;
    ct[idx] = cosf(f);
    st[idx] = sinf(f);
}

// ---------------- RoPE apply (in-place on bf16 rows) ----------------
__global__ void rope_apply_k(u16* __restrict__ x, const float* __restrict__ ct,
                             const float* __restrict__ st, int nrows, int rstride,
                             int roff, int rows_per_t) {
    int idx = blockIdx.x * 256 + threadIdx.x;
    if (idx >= nrows * 32) return;
    int row = idx >> 5, i = idx & 31;
    int t = (row / rows_per_t) % cfg::T;
    u16* p = x + (size_t)row * rstride + roff;
    float x1 = bf2f(p[i]), x2 = bf2f(p[32 + i]);
    float c = ct[t * 32 + i], s = st[t * 32 + i];
    p[i] = f2bf(x1 * c - x2 * s);
    p[32 + i] = f2bf(x2 * c + x1 * s);
}

// -------- V transpose: kv[b,t,h,128+d] -> vt[(b*H+h)*128+d][t] (bf16) --------
__global__ __launch_bounds__(256) void vtrans_k(const u16* __restrict__ kv,
                                                u16* __restrict__ vt) {
    using namespace cfg;
    __shared__ u16 tl[64][136];
    const int bh = blockIdx.x, t0 = blockIdx.y * 64;
    const int b = bh >> 4, h = bh & 15;
    const int tid = threadIdx.x;
#pragma unroll
    for (int it = 0; it < 4; ++it) {
        int id = tid + it * 256, r = id >> 4, c8 = id & 15;
        short8 v = *reinterpret_cast<const short8*>(
            kv + ((size_t)(b * T + t0 + r) * H + h) * 256 + 128 + c8 * 8);
        *reinterpret_cast<short8*>(&tl[r][c8 * 8]) = v;
    }
    __syncthreads();
#pragma unroll
    for (int it = 0; it < 4; ++it) {
        int id = tid + it * 256, d = id >> 3, tc = id & 7;
        short8 v;
#pragma unroll
        for (int j = 0; j < 8; ++j) v[j] = (short)tl[tc * 8 + j][d];
        *reinterpret_cast<short8*>(vt + ((size_t)bh * 128 + d) * T + t0 + tc * 8) = v;
    }
}

// ---------------- GEMM: C[M,N] = A[M,K] * Bt[N,K]^T (bf16 in, f32 acc) ----------------
// 2-phase double-buffered prefetch (T3 minimum recipe): STAGE(next, buf^1)
// issued before compute(buf); ONE __syncthreads per K-step (its vmcnt(0)
// drain covers the prefetch, which had the whole compute phase to land).
template <int BM, int BN, int BK, int WM, int WN, bool OUTF32>
__global__ __launch_bounds__((BM / WM) * (BN / WN) * 64) void gemm_bt_k(
    const u16* __restrict__ A, const u16* __restrict__ Bt, void* __restrict__ Cv,
    int M, int N, int K, float cscale) {
    constexpr int NW = (BM / WM) * (BN / WN);
    constexpr int MFR = WM / 16, NFR = WN / 16;
    constexpr int NWN = BN / WN;
    __shared__ u16 As[2][BM * BK];
    __shared__ u16 Bs[2][BN * BK];
    const int tid = threadIdx.x, lane = tid & 63, wid = tid >> 6;
    const int wr = wid / NWN, wc = wid % NWN;
    const int tM = blockIdx.x * BM, tN = blockIdx.y * BN;
    const int lr = lane & 15, hi = lane >> 4;
    f32x4 acc[MFR][NFR] = {};

    auto STAGE = [&](int k0, int buf) {
        constexpr int ACH = BM * BK * 2 / NW;  // bytes per wave
#pragma unroll
        for (int c = 0; c < ACH / 1024; ++c) {
            int loff = wid * ACH + c * 1024;
            int eidx = (loff >> 1) + lane * 8;
            const u16* src = A + (size_t)(tM + eidx / BK) * K + k0 + (eidx % BK);
            __builtin_amdgcn_global_load_lds(
                (const __attribute__((address_space(1))) void*)src,
                (__attribute__((address_space(3))) void*)((char*)As[buf] + loff), 16, 0, 0);
        }
        constexpr int BCH = BN * BK * 2 / NW;
#pragma unroll
        for (int c = 0; c < BCH / 1024; ++c) {
            int loff = wid * BCH + c * 1024;
            int eidx = (loff >> 1) + lane * 8;
            const u16* src = Bt + (size_t)(tN + eidx / BK) * K + k0 + (eidx % BK);
            __builtin_amdgcn_global_load_lds(
                (const __attribute__((address_space(1))) void*)src,
                (__attribute__((address_space(3))) void*)((char*)Bs[buf] + loff), 16, 0, 0);
        }
    };

    STAGE(0, 0);
    __syncthreads();
    int cur = 0;
    for (int k0 = 0; k0 < K; k0 += BK) {
        if (k0 + BK < K) STAGE(k0 + BK, cur ^ 1);
#pragma unroll
        for (int kk = 0; kk < BK / 32; ++kk) {
            bf16x8 af[MFR], bfv[NFR];
#pragma unroll
            for (int mi = 0; mi < MFR; ++mi)
                af[mi] = *reinterpret_cast<const bf16x8*>(&As[cur][(wr * WM + mi * 16 + lr) * BK + kk * 32 + hi * 8]);
#pragma unroll
            for (int ni = 0; ni < NFR; ++ni)
                bfv[ni] = *reinterpret_cast<const bf16x8*>(&Bs[cur][(wc * WN + ni * 16 + lr) * BK + kk * 32 + hi * 8]);
#pragma unroll
            for (int mi = 0; mi < MFR; ++mi)
#pragma unroll
                for (int ni = 0; ni < NFR; ++ni)
                    acc[mi][ni] = __builtin_amdgcn_mfma_f32_16x16x32_bf16(af[mi], bfv[ni], acc[mi][ni], 0, 0, 0);
        }
        __syncthreads();
        cur ^= 1;
    }
#pragma unroll
    for (int mi = 0; mi < MFR; ++mi)
#pragma unroll
        for (int ni = 0; ni < NFR; ++ni)
#pragma unroll
            for (int r = 0; r < 4; ++r) {
                int row = tM + wr * WM + mi * 16 + hi * 4 + r;
                int col = tN + wc * WN + ni * 16 + lr;
                float v = acc[mi][ni][r] * cscale;
                if (OUTF32)
                    ((float*)Cv)[(size_t)row * N + col] = v;
                else
                    ((u16*)Cv)[(size_t)row * N + col] = f2bf(v);
            }
}

// ---------------- Flash attention (causal, bf16, MFMA) ----------------
// QB=64, KB=64, 4 waves (16 q-rows each). One q-tile per block, biggest first.
// Q pre-scaled by (1/sqrt(192))*log2(e) -> P = exp2(S); fixed-max softmax.
// T14 async-STAGE: issue tile kb+1 global loads BEFORE compute(kb); after the
// read-barrier, write regs->LDS, barrier. Load latency hides under compute.
namespace acfg {
constexpr int QB = 64, KB = 64, KS = 200, VTS = 72, PS = 72;
constexpr int NQT = cfg::T / QB;  // 32
}
__global__ __launch_bounds__(256) void mla_attn_k(const u16* __restrict__ q,
                                                  const u16* __restrict__ kv,
                                                  const u16* __restrict__ kr, int krs,
                                                  const u16* __restrict__ vtg,
                                                  u16* __restrict__ o) {
    using namespace cfg;
    using namespace acfg;
    __shared__ u16 Ks[KB * KS];       // 64 x 192 (stride 200)
    __shared__ u16 Vt[DV * VTS];      // 128 x 64 (stride 72), pre-transposed
    __shared__ u16 Pl[4 * 16 * PS];   // per-wave 16 x 64 (stride 72)
    const int bid = blockIdx.x;
    const int bh = bid & 31;
    const int qt = NQT - 1 - (bid >> 5);  // biggest blocks first
    const int b = bh >> 4, h = bh & 15;
    const int q0 = qt * QB;
    const int tid = threadIdx.x, lane = tid & 63, w = tid >> 6;
    const int lr = lane & 15, hi = lane >> 4;

    bf16x8 qf[6];
    {
        int row = q0 + w * 16 + lr;
        const u16* qp = q + ((size_t)(b * T + row) * H + h) * DQK;
#pragma unroll
        for (int ks = 0; ks < 6; ++ks)
            qf[ks] = *reinterpret_cast<const bf16x8*>(qp + ks * 32 + hi * 8);
    }
    f32x4 oacc[8] = {};
    float lsum[4] = {0.f, 0.f, 0.f, 0.f};

    // staging registers (10 x 16B = 40 VGPR)
    short8 rkn[4], rkr[2], rv[4];
    auto LOADT = [&](int kb) {
        const int kt0 = kb * KB;
#pragma unroll
        for (int it = 0; it < 4; ++it) {
            int id = tid + it * 256, r = id >> 4, c8 = id & 15;
            rkn[it] = *reinterpret_cast<const short8*>(
                kv + ((size_t)(b * T + kt0 + r) * H + h) * 256 + c8 * 8);
        }
#pragma unroll
        for (int it = 0; it < 2; ++it) {
            int id = tid + it * 256, r = id >> 3, c8 = id & 7;
            rkr[it] = *reinterpret_cast<const short8*>(
                kr + (size_t)(b * T + kt0 + r) * krs + c8 * 8);
        }
#pragma unroll
        for (int it = 0; it < 4; ++it) {
            int id = tid + it * 256, d = id >> 3, c8 = id & 7;
            rv[it] = *reinterpret_cast<const short8*>(
                vtg + ((size_t)(b * H + h) * 128 + d) * T + kt0 + c8 * 8);
        }
    };
    auto WRITET = [&]() {
#pragma unroll
        for (int it = 0; it < 4; ++it) {
            int id = tid + it * 256, r = id >> 4, c8 = id & 15;
            *reinterpret_cast<short8*>(&Ks[r * KS + c8 * 8]) = rkn[it];
        }
#pragma unroll
        for (int it = 0; it < 2; ++it) {
            int id = tid + it * 256, r = id >> 3, c8 = id & 7;
            *reinterpret_cast<short8*>(&Ks[r * KS + 128 + c8 * 8]) = rkr[it];
        }
#pragma unroll
        for (int it = 0; it < 4; ++it) {
            int id = tid + it * 256, d = id >> 3, c8 = id & 7;
            *reinterpret_cast<short8*>(&Vt[d * VTS + c8 * 8]) = rv[it];
        }
    };

    const int nkb = qt + 1;
    LOADT(0);
    WRITET();
    __syncthreads();

#pragma unroll 1
    for (int kb = 0; kb < nkb; ++kb) {
        const int kt0 = kb * KB;
        const bool more = (kb + 1 < nkb);
        if (more) LOADT(kb + 1);  // issue early; consumed after the barrier

        // S = Q K^T  (per wave: 16 q-rows x 64 k-cols), already in log2 units
        f32x4 s[4] = {};
#pragma unroll
        for (int ks = 0; ks < 6; ++ks) {
            bf16x8 kf[4];
#pragma unroll
            for (int ni = 0; ni < 4; ++ni)
                kf[ni] = *reinterpret_cast<const bf16x8*>(&Ks[(ni * 16 + lr) * KS + ks * 32 + hi * 8]);
#pragma unroll
            for (int ni = 0; ni < 4; ++ni)
                s[ni] = __builtin_amdgcn_mfma_f32_16x16x32_bf16(qf[ks], kf[ni], s[ni], 0, 0, 0);
        }
        const bool diag = (kb == nkb - 1);
        if (diag) {
#pragma unroll
            for (int r = 0; r < 4; ++r) {
                int qr = q0 + w * 16 + hi * 4 + r;
#pragma unroll
                for (int ni = 0; ni < 4; ++ni) {
                    int kc = kt0 + ni * 16 + lr;
                    if (kc > qr) s[ni][r] = -INFINITY;
                }
            }
        }
        // fixed-max softmax: P = exp2(S); per-lane partial row sums
        u16* pw = &Pl[w * 16 * PS];
#pragma unroll
        for (int r = 0; r < 4; ++r) {
            float p0 = exp2f(s[0][r]);
            float p1 = exp2f(s[1][r]);
            float p2 = exp2f(s[2][r]);
            float p3 = exp2f(s[3][r]);
            lsum[r] += (p0 + p1) + (p2 + p3);
            pw[(hi * 4 + r) * PS + 0 * 16 + lr] = __builtin_bit_cast(u16, (__bf16)p0);
            pw[(hi * 4 + r) * PS + 1 * 16 + lr] = __builtin_bit_cast(u16, (__bf16)p1);
            pw[(hi * 4 + r) * PS + 2 * 16 + lr] = __builtin_bit_cast(u16, (__bf16)p2);
            pw[(hi * 4 + r) * PS + 3 * 16 + lr] = __builtin_bit_cast(u16, (__bf16)p3);
        }
        // PV
#pragma unroll
        for (int kk = 0; kk < 2; ++kk) {
            bf16x8 pf = *reinterpret_cast<const bf16x8*>(&pw[lr * PS + kk * 32 + hi * 8]);
#pragma unroll
            for (int ni = 0; ni < 8; ++ni) {
                bf16x8 vf = *reinterpret_cast<const bf16x8*>(&Vt[(ni * 16 + lr) * VTS + kk * 32 + hi * 8]);
                oacc[ni] = __builtin_amdgcn_mfma_f32_16x16x32_bf16(pf, vf, oacc[ni], 0, 0, 0);
            }
        }
        __syncthreads();  // all reads of Ks/Vt done
        if (more) {
            WRITET();      // waits on the early loads via register deps
            __syncthreads();
        }
    }
    // final row-sum reduce across the 16-lane group, then normalize + store
    float ltot[4];
#pragma unroll
    for (int r = 0; r < 4; ++r) {
        float sumv = lsum[r];
        sumv += __shfl_xor(sumv, 1);
        sumv += __shfl_xor(sumv, 2);
        sumv += __shfl_xor(sumv, 4);
        sumv += __shfl_xor(sumv, 8);
        ltot[r] = 1.f / sumv;
    }
#pragma unroll
    for (int ni = 0; ni < 8; ++ni)
#pragma unroll
        for (int r = 0; r < 4; ++r) {
            int row = q0 + w * 16 + hi * 4 + r;
            int col = ni * 16 + lr;
            float v = oacc[ni][r] * ltot[r];
            o[((size_t)(b * T + row) * H + h) * DV + col] = f2bf(v);
        }
}

// ---------------- workspace layout ----------------
namespace wso {
using namespace cfg;
constexpr size_t O_HSVT = 0;  // hs_b (stage-1 input), later aliased by vt
constexpr size_t O_WCAT = O_HSVT + (size_t)BT * D * 2;
constexpr size_t O_WQB  = O_WCAT + (size_t)NCAT * D * 2;
constexpr size_t O_WKVB = O_WQB  + (size_t)HD * QL * 2;
constexpr size_t O_WO   = O_WKVB + (size_t)KVD * KVL * 2;
constexpr size_t O_QAKR = O_WO   + (size_t)D * D * 2;
constexpr size_t O_QAN  = O_QAKR + (size_t)BT * NCAT * 2;
constexpr size_t O_KVAN = O_QAN;  // alias: qan dead before kvan is written
constexpr size_t O_QB   = O_QAN  + (size_t)BT * QL * 2;
constexpr size_t O_KV   = O_QB   + (size_t)BT * HD * 2;
constexpr size_t O_COS  = O_KV   + (size_t)BT * KVD * 2;
constexpr size_t O_SIN  = O_COS  + (size_t)T * 32 * 4;
constexpr size_t O_OB   = O_SIN  + (size_t)T * 32 * 4;
}

extern "C" void kernel_launch(void* const* d_in, const int* in_sizes, int n_in,
                              void* d_out, int out_size, void* d_ws, size_t ws_size,
                              hipStream_t stream) {
    using namespace cfg;
    using namespace wso;
    (void)in_sizes; (void)n_in; (void)out_size; (void)ws_size;

    const float* hs   = (const float*)d_in[0];
    const float* Wqa  = (const float*)d_in[1];
    const float* qnw  = (const float*)d_in[2];
    const float* Wqb  = (const float*)d_in[3];
    const float* Wkr  = (const float*)d_in[4];
    const float* Wkva = (const float*)d_in[5];
    const float* kvnw = (const float*)d_in[6];
    const float* Wkvb = (const float*)d_in[7];
    const float* Wo   = (const float*)d_in[8];

    char* ws = (char*)d_ws;
    u16* hs_b   = (u16*)(ws + O_HSVT);
    u16* vtg    = (u16*)(ws + O_HSVT);  // alias: hs_b dead after stage-1 GEMM
    u16* wcat   = (u16*)(ws + O_WCAT);
    u16* wqb_t  = (u16*)(ws + O_WQB);
    u16* wkvb_t = (u16*)(ws + O_WKVB);
    u16* wo_t   = (u16*)(ws + O_WO);
    u16* qakr   = (u16*)(ws + O_QAKR);
    u16* qan    = (u16*)(ws + O_QAN);
    u16* kvan   = (u16*)(ws + O_KVAN);
    u16* qb     = (u16*)(ws + O_QB);
    u16* kvb    = (u16*)(ws + O_KV);
    float* cost = (float*)(ws + O_COS);
    float* sint = (float*)(ws + O_SIN);
    u16* ob     = (u16*)(ws + O_OB);

    // attention score scale * log2(e), folded into Q via the q_b GEMM epilogue
    const float qesc = 0.07216878364870323f * 1.4426950408889634f;

    // 1. convert hidden to bf16
    cvt_bf16_k<<<2048, 256, 0, stream>>>(hs, hs_b, BT * D / 4);
    // 2. transpose-convert weights; wcat = [Wq_a | Wkv_a | Wk_rope]^T rows
    transpose_cvt_k<<<dim3(QL / 32, D / 32), 256, 0, stream>>>(Wqa, wcat, D, QL);
    transpose_cvt_k<<<dim3(KVL / 32, D / 32), 256, 0, stream>>>(Wkva, wcat + (size_t)QL * D, D, KVL);
    transpose_cvt_k<<<dim3(DROPE / 32, D / 32), 256, 0, stream>>>(Wkr, wcat + (size_t)(QL + KVL) * D, D, DROPE);
    transpose_cvt_k<<<dim3(HD / 32, QL / 32), 256, 0, stream>>>(Wqb, wqb_t, QL, HD);
    transpose_cvt_k<<<dim3(KVD / 32, KVL / 32), 256, 0, stream>>>(Wkvb, wkvb_t, KVL, KVD);
    transpose_cvt_k<<<dim3(D / 32, D / 32), 256, 0, stream>>>(Wo, wo_t, D, D);
    // 3. rope tables
    rope_tab_k<<<T * 32 / 256, 256, 0, stream>>>(cost, sint);
    // 4. fused stage-1: qakr = hidden @ [Wq_a|Wkv_a|Wk_rope]
    gemm_bt_k<128, 128, 32, 64, 64, false><<<dim3(BT / 128, NCAT / 128), 256, 0, stream>>>(
        hs_b, wcat, qakr, BT, NCAT, D, 1.f);
    // 5. q branch: rmsnorm -> q_b (epilogue-scaled by qesc) -> rope
    rmsnorm_k<<<BT, 256, 0, stream>>>(qakr, qnw, qan, QL, NCAT);
    gemm_bt_k<128, 128, 32, 64, 64, false><<<dim3(BT / 128, HD / 128), 256, 0, stream>>>(
        qan, wqb_t, qb, BT, HD, QL, qesc);
    rope_apply_k<<<BT * H * 32 / 256, 256, 0, stream>>>(qb, cost, sint, BT * H, DQK, 128, H);
    // 6. kv branch: rmsnorm -> kv_b
    rmsnorm_k<<<BT, 256, 0, stream>>>(qakr + QL, kvnw, kvan, KVL, NCAT);
    gemm_bt_k<128, 128, 32, 64, 64, false><<<dim3(BT / 128, KVD / 128), 256, 0, stream>>>(
        kvan, wkvb_t, kvb, BT, KVD, KVL, 1.f);
    // 7. rope on k_rope slice (in place in qakr)
    rope_apply_k<<<BT * 32 / 256, 256, 0, stream>>>(qakr + QL + KVL, cost, sint, BT, NCAT, 0, 1);
    // 8. global V transpose, then attention (1 q-tile/block, biggest first)
    vtrans_k<<<dim3(B * H, T / 64), 256, 0, stream>>>(kvb, vtg);
    mla_attn_k<<<32 * acfg::NQT, 256, 0, stream>>>(qb, kvb, qakr + QL + KVL, NCAT, vtg, ob);
    // 9. out = o @ Wo  (f32 out)
    gemm_bt_k<128, 128, 32, 64, 64, true><<<dim3(BT / 128, D / 128), 256, 0, stream>>>(
        ob, wo_t, d_out, BT, D, H * DV, 1.f);
}